// Round 5
// baseline (18999.565 us; speedup 1.0000x reference)
//
#include <hip/hip_runtime.h>
#include <stdint.h>

#define HID 1024
#define NGATE 4096
#define BATCH 256
#define TENC 128
#define VOCAB 1024
#define NOUT 125
#define TDEC (16 + NOUT)   // 141
#define MAXTHINK 16
#define STOPCLS 1023
#define CH 8               // encoder chunk (timesteps per big x-GEMM)

typedef __attribute__((ext_vector_type(8))) short short8;
typedef __attribute__((ext_vector_type(4))) float f32x4;

// ---------------- threefry2x32 (exact JAX partitionable semantics) ----------------
__device__ __forceinline__ uint32_t rotl32(uint32_t v, int r){ return (v<<r)|(v>>(32-r)); }

__device__ __forceinline__ void tf2x32(uint32_t k0, uint32_t k1, uint32_t x0, uint32_t x1,
                                       uint32_t& o0, uint32_t& o1)
{
  uint32_t k2 = k0 ^ k1 ^ 0x1BD11BDAu;
  x0 += k0; x1 += k1;
#define R4(a,b,cc,d) x0+=x1;x1=rotl32(x1,a);x1^=x0; x0+=x1;x1=rotl32(x1,b);x1^=x0; \
                     x0+=x1;x1=rotl32(x1,cc);x1^=x0; x0+=x1;x1=rotl32(x1,d);x1^=x0;
  R4(13,15,26,6)  x0+=k1; x1+=k2+1u;
  R4(17,29,16,24) x0+=k2; x1+=k0+2u;
  R4(13,15,26,6)  x0+=k0; x1+=k1+3u;
  R4(17,29,16,24) x0+=k1; x1+=k2+4u;
  R4(13,15,26,6)  x0+=k2; x1+=k0+5u;
#undef R4
  o0 = x0; o1 = x1;
}

__device__ __forceinline__ uint32_t jax_bits(uint32_t fk0, uint32_t fk1, uint32_t i)
{
  uint32_t o0, o1;
  tf2x32(fk0, fk1, 0u, i, o0, o1);   // 64-bit iota: hi=0, lo=i
  return o0 ^ o1;                     // XOR-fold (jax_threefry_partitionable)
}

__device__ __forceinline__ float sigm(float x){ return 0.5f + 0.5f*tanhf(0.5f*x); }

__device__ __forceinline__ ushort bf16rn(float v){
  uint32_t u = __float_as_uint(v);
  uint32_t r = (u + 0x7fffu + ((u>>16)&1u)) >> 16;
  return (ushort)r;
}
__device__ __forceinline__ float bf16tof(ushort s){ return __uint_as_float(((uint32_t)s)<<16); }

// ---------------- prep ----------------
__global__ __launch_bounds__(256) void prep_kernel(
    const float* __restrict__ b_ih, const float* __restrict__ b_hh,
    const float* __restrict__ x, const int* __restrict__ lengths,
    float* __restrict__ bsum, float* __restrict__ h, float* __restrict__ c,
    float* __restrict__ cur, int* __restrict__ is_think0,
    int* __restrict__ think_steps, int* __restrict__ out_steps,
    ushort* __restrict__ h3, ushort* __restrict__ cur3)
{
  int idx = blockIdx.x*256 + threadIdx.x;           // 0 .. 262143
  if (idx < NGATE) bsum[idx] = b_ih[idx] + b_hh[idx];
  if (idx < BATCH){ is_think0[idx] = 1; think_steps[idx] = 0; out_steps[idx] = 0; }
  h[idx] = 0.f; c[idx] = 0.f;
  if (h3){
    #pragma unroll
    for (int p=0;p<3;p++) h3[p*262144 + idx] = 0;
  }
  int b = idx >> 10, k = idx & (HID-1);
  int L = lengths[b];
  float cv = x[((size_t)b*TENC + (size_t)(L-1))*HID + k];
  cur[idx] = cv;
  if (cur3){
    float v = cv;
    #pragma unroll
    for (int p=0;p<3;p++){ ushort pp = bf16rn(v); v -= bf16tof(pp); cur3[p*262144 + idx] = pp; }
  }
}

// ---------------- weight pre-split into frag-ordered bf16 planes ----------------
// Wf[p][nt=n/16][kc=k/8][fr=n&15][ke=k&7]; plane stride = N*1024 elements
__global__ __launch_bounds__(256) void splitw_kernel(
    const float* __restrict__ W, ushort* __restrict__ Wf, int N)
{
  int idx = blockIdx.x*256 + threadIdx.x;   // n*128 + kc
  int n = idx >> 7, kc = idx & 127;
  float v[8];
  *(float4*)&v[0] = *(const float4*)(W + (size_t)n*1024 + kc*8);
  *(float4*)&v[4] = *(const float4*)(W + (size_t)n*1024 + kc*8 + 4);
  size_t base = ((size_t)(n>>4)*128 + kc)*128 + (n&15)*8;
  #pragma unroll
  for (int p=0;p<3;p++){
    ushort o[8];
    #pragma unroll
    for (int e=0;e<8;e++){ ushort pp = bf16rn(v[e]); v[e] -= bf16tof(pp); o[e] = pp; }
    *(uint4*)(Wf + (size_t)p*N*1024 + base) = *(uint4*)o;
  }
}

// ---------------- encoder x chunk split: xs3[p][j*256+b][k] = split(x[b][t0+j][k]) ----------------
__global__ __launch_bounds__(256) void xsplit_kernel(
    const float* __restrict__ x, ushort* __restrict__ xs3, int t0)
{
  int idx = blockIdx.x*256 + threadIdx.x;   // row*256 + k4
  int row = idx >> 8, k4 = (idx & 255) << 2;
  int b = row & 255, jj = row >> 8;
  float v[4];
  *(float4*)v = *(const float4*)(x + ((size_t)b*TENC + t0 + jj)*HID + k4);
  #pragma unroll
  for (int p=0;p<3;p++){
    ushort o[4];
    #pragma unroll
    for (int e=0;e<4;e++){ ushort pp = bf16rn(v[e]); v[e] -= bf16tof(pp); o[e] = pp; }
    *(uint2*)(xs3 + (size_t)p*CH*BATCH*1024 + (size_t)row*1024 + k4) = *(uint2*)o;
  }
}

// ---------------- pre-split GEMM: A planes [PL][AM][1024], W frag-ordered planes ----------------
// C[m][n] = sum_k A[m][k]*W[n][k]. Tile 64x64, 4 waves 2x2, single-barrier LDS dbuf for A,
// W fragments loaded direct global->reg (coalesced 1KB/wave). XCD-swizzled 1D grid.
template<int PL>
__global__ __launch_bounds__(256) void gemm_ps(
    const ushort* __restrict__ A1, int Am1,
    const ushort* __restrict__ A2,
    const ushort* __restrict__ Wf1, const ushort* __restrict__ Wf2,
    float* __restrict__ C0, float* __restrict__ C1,
    int N, int Mtiles, int Ntiles, int Z)
{
  int id = blockIdx.x;
  int xcd = id & 7, s = id >> 3;
  int b = s % Mtiles;
  int G = (s / Mtiles) * 8 + xcd;      // sharer group (z,j) -> same XCD for all b
  int z = G / Ntiles, j = G % Ntiles;

  const ushort* A = z ? A2 : A1;
  int AM = z ? BATCH : Am1;
  const ushort* Wf = z ? Wf2 : Wf1;
  float* C = z ? C1 : C0;
  int j0 = j << 6, b0 = b << 6;

  __shared__ __align__(16) ushort As[2][PL][64][40];
  int tid = threadIdx.x, lane = tid & 63, w = tid >> 6;
  int mb = (w >> 1) << 5, nb = (w & 1) << 5;
  int fr = lane & 15, q = lane >> 4;
  int arow = tid >> 2, aq = tid & 3;

  const ushort* Ap = A + (size_t)(b0 + arow)*1024 + aq*8;
  size_t aps = (size_t)AM * 1024;

  uint4 sv[PL];
  #pragma unroll
  for (int p=0;p<PL;p++) sv[p] = *(const uint4*)(Ap + p*aps);

  const ushort* wbase[PL][2];
  #pragma unroll
  for (int p=0;p<PL;p++)
    #pragma unroll
    for (int f=0;f<2;f++)
      wbase[p][f] = Wf + (size_t)p*N*1024
                  + ((size_t)(((j0+nb)>>4) + f)*128 + q)*128 + fr*8;

  f32x4 acc[2][2] = {};
  int cb = 0;
  for (int kc0 = 0; kc0 < 128; kc0 += 4){   // k0 = kc0*8, 32 k-iters
    #pragma unroll
    for (int p=0;p<PL;p++) *(uint4*)&As[cb][p][arow][aq*8] = sv[p];
    __syncthreads();
    if (kc0 + 4 < 128){
      #pragma unroll
      for (int p=0;p<PL;p++) sv[p] = *(const uint4*)(Ap + p*aps + (kc0+4)*8);
    }
    short8 afr[PL][2], bfr[PL][2];
    #pragma unroll
    for (int p=0;p<PL;p++)
      #pragma unroll
      for (int f=0;f<2;f++){
        bfr[p][f] = *(const short8*)(wbase[p][f] + (size_t)kc0*128);
        afr[p][f] = *(const short8*)&As[cb][p][mb + f*16 + fr][q*8];
      }
    #pragma unroll
    for (int f=0;f<2;f++)
      #pragma unroll
      for (int g=0;g<2;g++){
        if constexpr (PL==3){
          acc[f][g] = __builtin_amdgcn_mfma_f32_16x16x32_bf16(afr[2][f], bfr[0][g], acc[f][g], 0,0,0);
          acc[f][g] = __builtin_amdgcn_mfma_f32_16x16x32_bf16(afr[1][f], bfr[1][g], acc[f][g], 0,0,0);
          acc[f][g] = __builtin_amdgcn_mfma_f32_16x16x32_bf16(afr[0][f], bfr[2][g], acc[f][g], 0,0,0);
          acc[f][g] = __builtin_amdgcn_mfma_f32_16x16x32_bf16(afr[1][f], bfr[0][g], acc[f][g], 0,0,0);
          acc[f][g] = __builtin_amdgcn_mfma_f32_16x16x32_bf16(afr[0][f], bfr[1][g], acc[f][g], 0,0,0);
          acc[f][g] = __builtin_amdgcn_mfma_f32_16x16x32_bf16(afr[0][f], bfr[0][g], acc[f][g], 0,0,0);
        } else {
          acc[f][g] = __builtin_amdgcn_mfma_f32_16x16x32_bf16(afr[0][f], bfr[0][g], acc[f][g], 0,0,0);
        }
      }
    cb ^= 1;
  }
  int crow = q*4, ccol = fr;
  #pragma unroll
  for (int f=0;f<2;f++)
    #pragma unroll
    for (int g=0;g<2;g++)
      #pragma unroll
      for (int r=0;r<4;r++)
        C[(size_t)(b0 + mb + f*16 + crow + r)*N + (j0 + nb + g*16 + ccol)] = acc[f][g][r];
}

// ---------------- round-4 fallback GEMM (in-kernel split) ----------------
template<int PL>
__global__ __launch_bounds__(256) void gemm_mfma(
    const float* __restrict__ A1, int lda1,
    const float* __restrict__ A2,
    const float* __restrict__ W1, const float* __restrict__ W2,
    float* __restrict__ C0, float* __restrict__ C1, int N)
{
  int z = blockIdx.z;
  const float* A = z ? A2 : A1;
  const float* W = z ? W2 : W1;
  int lda = z ? HID : lda1;
  float* C = z ? C1 : C0;

  __shared__ __align__(16) ushort As[PL][64][40];
  __shared__ __align__(16) ushort Ws[PL][64][40];

  int tid  = threadIdx.x;
  int lane = tid & 63;
  int w    = tid >> 6;
  int j0 = blockIdx.x * 64;
  int b0 = blockIdx.y * 64;
  int srow = tid >> 2;
  int skp  = (tid & 3) * 8;
  int mb = (w >> 1) * 32;
  int nb = (w & 1) * 32;
  int fr = lane & 15;
  int ko = (lane >> 4) * 8;

  f32x4 acc[2][2] = {};

  for (int k0 = 0; k0 < HID; k0 += 32){
    const float* ap = A + (size_t)(b0+srow)*lda + k0 + skp;
    const float* wp = W + (size_t)(j0+srow)*HID + k0 + skp;
    float av[8], wv[8];
    *(float4*)&av[0] = *(const float4*)ap;  *(float4*)&av[4] = *(const float4*)(ap+4);
    *(float4*)&wv[0] = *(const float4*)wp;  *(float4*)&wv[4] = *(const float4*)(wp+4);
    __syncthreads();
    #pragma unroll
    for (int e=0;e<8;e++){
      float va = av[e], vw = wv[e];
      #pragma unroll
      for (int p=0;p<PL;p++){
        ushort pa = bf16rn(va); va -= bf16tof(pa); As[p][srow][skp+e] = pa;
        ushort pw = bf16rn(vw); vw -= bf16tof(pw); Ws[p][srow][skp+e] = pw;
      }
    }
    __syncthreads();
    short8 a[PL][2], b[PL][2];
    #pragma unroll
    for (int p=0;p<PL;p++)
      #pragma unroll
      for (int f=0;f<2;f++){
        a[p][f] = *(const short8*)&As[p][mb + f*16 + fr][ko];
        b[p][f] = *(const short8*)&Ws[p][nb + f*16 + fr][ko];
      }
    #pragma unroll
    for (int f=0;f<2;f++)
      #pragma unroll
      for (int g=0;g<2;g++){
        if constexpr (PL==3){
          acc[f][g] = __builtin_amdgcn_mfma_f32_16x16x32_bf16(a[2][f], b[0][g], acc[f][g], 0,0,0);
          acc[f][g] = __builtin_amdgcn_mfma_f32_16x16x32_bf16(a[1][f], b[1][g], acc[f][g], 0,0,0);
          acc[f][g] = __builtin_amdgcn_mfma_f32_16x16x32_bf16(a[0][f], b[2][g], acc[f][g], 0,0,0);
          acc[f][g] = __builtin_amdgcn_mfma_f32_16x16x32_bf16(a[1][f], b[0][g], acc[f][g], 0,0,0);
          acc[f][g] = __builtin_amdgcn_mfma_f32_16x16x32_bf16(a[0][f], b[1][g], acc[f][g], 0,0,0);
          acc[f][g] = __builtin_amdgcn_mfma_f32_16x16x32_bf16(a[0][f], b[0][g], acc[f][g], 0,0,0);
        } else {
          acc[f][g] = __builtin_amdgcn_mfma_f32_16x16x32_bf16(a[0][f], b[0][g], acc[f][g], 0,0,0);
        }
      }
  }
  int crow = (lane >> 4) * 4;
  int ccol = lane & 15;
  #pragma unroll
  for (int f=0;f<2;f++)
    #pragma unroll
    for (int g=0;g<2;g++)
      #pragma unroll
      for (int r=0;r<4;r++)
        C[(size_t)(b0 + mb + f*16 + crow + r)*N + (j0 + nb + g*16 + ccol)] = acc[f][g][r];
}

// ---------------- LSTM cell elementwise ----------------
__global__ __launch_bounds__(256) void cell_kernel(
    const float* __restrict__ g0, const float* __restrict__ g1, const float* __restrict__ bsum,
    float* __restrict__ h, float* __restrict__ c, ushort* __restrict__ h3,
    const int* __restrict__ lengths, int t)
{
  int idx = blockIdx.x*256 + threadIdx.x;
  int b = idx >> 10, k = idx & (HID-1);
  if (lengths && t >= lengths[b]) return;
  size_t base = (size_t)b*NGATE + k;
  float gi = g0[base       ] + g1[base       ] + bsum[k       ];
  float gf = g0[base + 1024] + g1[base + 1024] + bsum[k + 1024];
  float gg = g0[base + 2048] + g1[base + 2048] + bsum[k + 2048];
  float go = g0[base + 3072] + g1[base + 3072] + bsum[k + 3072];
  float cc = c[idx];
  float cn = sigm(gf)*cc + sigm(gi)*tanhf(gg);
  float hn = sigm(go)*tanhf(cn);
  c[idx] = cn; h[idx] = hn;
  if (h3){
    float v = hn;
    #pragma unroll
    for (int p=0;p<3;p++){ ushort pp = bf16rn(v); v -= bf16tof(pp); h3[p*262144 + idx] = pp; }
  }
}

// ---------------- out-phase cell: x-side one-hot -> W_ih column gather ----------------
__global__ __launch_bounds__(256) void cell_out_kernel(
    const float* __restrict__ g1, const float* __restrict__ bsum,
    const float* __restrict__ W_ih, const int* __restrict__ pred,
    float* __restrict__ h, float* __restrict__ c, ushort* __restrict__ h3)
{
  int idx = blockIdx.x*256 + threadIdx.x;
  int b = idx >> 10, k = idx & (HID-1);
  int p = pred[b];
  size_t base = (size_t)b*NGATE + k;
  float gi = g1[base       ] + W_ih[(size_t)(k       )*HID + p] + bsum[k       ];
  float gf = g1[base + 1024] + W_ih[(size_t)(k + 1024)*HID + p] + bsum[k + 1024];
  float gg = g1[base + 2048] + W_ih[(size_t)(k + 2048)*HID + p] + bsum[k + 2048];
  float go = g1[base + 3072] + W_ih[(size_t)(k + 3072)*HID + p] + bsum[k + 3072];
  float cc = c[idx];
  float cn = sigm(gf)*cc + sigm(gi)*tanhf(gg);
  float hn = sigm(go)*tanhf(cn);
  c[idx] = cn; h[idx] = hn;
  if (h3){
    float v = hn;
    #pragma unroll
    for (int pl=0;pl<3;pl++){ ushort pp = bf16rn(v); v -= bf16tof(pp); h3[pl*262144 + idx] = pp; }
  }
}

// ---------------- decode step ----------------
__global__ __launch_bounds__(256) void decide_kernel(
    const float* __restrict__ logits_raw, const float* __restrict__ b_fc, int t,
    const int* __restrict__ is_think_old, int* __restrict__ is_think_new,
    int* __restrict__ think_steps, int* __restrict__ out_steps,
    int* __restrict__ pred_out,
    float* __restrict__ cur, float* __restrict__ out, ushort* __restrict__ cur3)
{
  int b = blockIdx.x, tid = threadIdx.x;
  uint32_t fk0, fk1; tf2x32(0u, 42u, 0u, (uint32_t)t, fk0, fk1);

  float lg[4];
  float zb = -3.4e38f; int ib = 0;
  #pragma unroll
  for (int q=0;q<4;q++){
    int v = tid + (q<<8);
    uint32_t i = (uint32_t)(b*VOCAB + v);
    uint32_t bits = jax_bits(fk0, fk1, i);
    float f = __uint_as_float((bits>>9) | 0x3F800000u) - 1.0f;
    const float TINY = 1.17549435e-38f;
    float u = fmaxf(TINY, f + TINY);
    float g = -logf(-logf(u));
    float l = logits_raw[(size_t)b*VOCAB + v] + b_fc[v];
    lg[q] = l;
    float zz = l + g;
    if (zz > zb){ zb = zz; ib = v; }
  }

  __shared__ float smax[256]; __shared__ int sidxs[256];
  __shared__ int s_any, s_pred, s_outp, s_stepidx;
  smax[tid]=zb; sidxs[tid]=ib;
  if (tid==0) s_any = 0;
  __syncthreads();
  if (is_think_old[tid]) atomicOr(&s_any, 1);
  __syncthreads();
  for (int s=128;s>0;s>>=1){
    if (tid < s){
      float om=smax[tid+s]; int oi=sidxs[tid+s];
      if (om > smax[tid] || (om==smax[tid] && oi < sidxs[tid])){ smax[tid]=om; sidxs[tid]=oi; }
    }
    __syncthreads();
  }
  if (tid==0){
    int pred = sidxs[0]; s_pred = pred;
    pred_out[b] = pred;
    int isth = is_think_old[b];
    int os = out_steps[b];
    int outp = (!isth && os < NOUT) ? 1 : 0;
    s_outp = outp;
    s_stepidx = os < (NOUT-1) ? os : (NOUT-1);
    int nts = think_steps[b] + (isth ? 1 : 0);
    out_steps[b] = os + outp;
    think_steps[b] = nts;
    int jf = (isth && ((pred==STOPCLS) || (nts >= MAXTHINK))) ? 1 : 0;
    is_think_new[b] = (isth && !jf) ? 1 : 0;
    if (t == TDEC-1) out[(size_t)BATCH*NOUT*(VOCAB-1) + b] = (float)nts;
  }
  __syncthreads();
  int any = s_any, pred = s_pred, outp = s_outp, si = s_stepidx;
  #pragma unroll
  for (int q=0;q<4;q++){
    int v = tid + (q<<8);
    float l = lg[q];
    float cv = any ? l : (v==pred ? 1.0f : 0.0f);
    cur[(size_t)b*VOCAB + v] = cv;
    if (cur3){
      float t2 = cv;
      #pragma unroll
      for (int p=0;p<3;p++){ ushort pp = bf16rn(t2); t2 -= bf16tof(pp); cur3[p*262144 + b*1024 + v] = pp; }
    }
    if (outp && v < (VOCAB-1))
      out[((size_t)b*NOUT + si)*(VOCAB-1) + v] = l;
  }
}

// ---------------- host ----------------
extern "C" void kernel_launch(void* const* d_in, const int* in_sizes, int n_in,
                              void* d_out, int out_size, void* d_ws, size_t ws_size,
                              hipStream_t stream)
{
  const float* x    = (const float*)d_in[0];
  const float* W_ih = (const float*)d_in[1];
  const float* W_hh = (const float*)d_in[2];
  const float* b_ih = (const float*)d_in[3];
  const float* b_hh = (const float*)d_in[4];
  const float* W_fc = (const float*)d_in[5];
  const float* b_fc = (const float*)d_in[6];
  const int*   lengths = (const int*)d_in[7];
  float* out = (float*)d_out;
  char* W = (char*)d_ws;

  // ---- main-path layout (bytes) ----
  constexpr size_t OF_BSUM  = 0;
  constexpr size_t OF_H     = OF_BSUM  + 16384;
  constexpr size_t OF_C     = OF_H     + 1048576;
  constexpr size_t OF_CUR   = OF_C     + 1048576;
  constexpr size_t OF_LG    = OF_CUR   + 1048576;
  constexpr size_t OF_G1    = OF_LG    + 1048576;
  constexpr size_t OF_XG    = OF_G1    + 4194304;                  // 8 slots x 4MB (also g0)
  constexpr size_t OF_H3    = OF_XG    + (size_t)CH*4194304;
  constexpr size_t OF_CUR3  = OF_H3    + 1572864;
  constexpr size_t OF_XS3   = OF_CUR3  + 1572864;
  constexpr size_t OF_WIH3  = OF_XS3   + (size_t)3*CH*BATCH*1024*2;
  constexpr size_t OF_WHH3  = OF_WIH3  + (size_t)3*NGATE*1024*2;
  constexpr size_t OF_WFC3  = OF_WHH3  + (size_t)3*NGATE*1024*2;
  constexpr size_t OF_INTS  = OF_WFC3  + (size_t)3*VOCAB*1024*2;
  constexpr size_t NEEDED   = OF_INTS  + 16384;

  if (ws_size >= NEEDED){
    float* bsum   = (float*)(W + OF_BSUM);
    float* h      = (float*)(W + OF_H);
    float* c      = (float*)(W + OF_C);
    float* cur    = (float*)(W + OF_CUR);
    float* logits = (float*)(W + OF_LG);
    float* g1     = (float*)(W + OF_G1);
    float* xg     = (float*)(W + OF_XG);
    float* g0     = xg;                       // reused in think phase
    ushort* h3    = (ushort*)(W + OF_H3);
    ushort* cur3  = (ushort*)(W + OF_CUR3);
    ushort* xs3   = (ushort*)(W + OF_XS3);
    ushort* wih3  = (ushort*)(W + OF_WIH3);
    ushort* whh3  = (ushort*)(W + OF_WHH3);
    ushort* wfc3  = (ushort*)(W + OF_WFC3);
    int* ints = (int*)(W + OF_INTS);
    int* is_think    = ints;
    int* think_steps = ints + 512;
    int* out_steps   = ints + 768;
    int* pred        = ints + 1024;

    splitw_kernel<<<NGATE/2, 256, 0, stream>>>(W_ih, wih3, NGATE);
    splitw_kernel<<<NGATE/2, 256, 0, stream>>>(W_hh, whh3, NGATE);
    splitw_kernel<<<VOCAB/2, 256, 0, stream>>>(W_fc, wfc3, VOCAB);
    prep_kernel<<<1024, 256, 0, stream>>>(b_ih, b_hh, x, lengths, bsum, h, c, cur,
                                          is_think, think_steps, out_steps, h3, cur3);

    for (int tc = 0; tc < TENC/CH; ++tc){
      xsplit_kernel<<<CH*BATCH, 256, 0, stream>>>(x, xs3, tc*CH);
      gemm_ps<3><<<64*(CH*BATCH/64), 256, 0, stream>>>(xs3, CH*BATCH, nullptr, wih3, nullptr,
                                                       xg, nullptr, NGATE, CH*BATCH/64, 64, 1);
      for (int tt = 0; tt < CH; ++tt){
        int t = tc*CH + tt;
        gemm_ps<3><<<256, 256, 0, stream>>>(h3, BATCH, nullptr, whh3, nullptr,
                                            g1, nullptr, NGATE, 4, 64, 1);
        cell_kernel<<<1024, 256, 0, stream>>>(xg + (size_t)tt*BATCH*NGATE, g1, bsum,
                                              h, c, h3, lengths, t);
      }
    }
    for (int t = 0; t < TDEC; ++t){
      if (t < MAXTHINK){
        gemm_ps<3><<<512, 256, 0, stream>>>(cur3, BATCH, h3, wih3, whh3,
                                            g0, g1, NGATE, 4, 64, 2);
        cell_kernel<<<1024, 256, 0, stream>>>(g0, g1, bsum, h, c, h3, nullptr, 0);
        gemm_ps<3><<<64, 256, 0, stream>>>(h3, BATCH, nullptr, wfc3, nullptr,
                                           logits, nullptr, VOCAB, 4, 16, 1);
      } else {
        gemm_ps<1><<<256, 256, 0, stream>>>(h3, BATCH, nullptr, whh3, nullptr,
                                            g1, nullptr, NGATE, 4, 64, 1);
        cell_out_kernel<<<1024, 256, 0, stream>>>(g1, bsum, W_ih, pred, h, c, h3);
        gemm_ps<1><<<64, 256, 0, stream>>>(h3, BATCH, nullptr, wfc3, nullptr,
                                           logits, nullptr, VOCAB, 4, 16, 1);
      }
      decide_kernel<<<BATCH, 256, 0, stream>>>(logits, b_fc, t,
                                               is_think + (t&1)*BATCH, is_think + ((t+1)&1)*BATCH,
                                               think_steps, out_steps, pred, cur, out,
                                               (t < MAXTHINK) ? cur3 : nullptr);
    }
    return;
  }

  // ---- fallback: round-4 path (verbatim behavior) ----
  float* ws   = (float*)d_ws;
  float* bsum = ws;
  float* h    = bsum + NGATE;
  float* c    = h + (size_t)BATCH*HID;
  float* g0   = c + (size_t)BATCH*HID;
  float* g1   = g0 + (size_t)BATCH*NGATE;
  float* cur  = g1 + (size_t)BATCH*NGATE;
  float* logits = cur + (size_t)BATCH*HID;
  int* ints = (int*)(logits + (size_t)BATCH*HID);
  int* is_think    = ints;
  int* think_steps = ints + 512;
  int* out_steps   = ints + 768;
  int* pred        = ints + 1024;

  prep_kernel<<<1024, 256, 0, stream>>>(b_ih, b_hh, x, lengths, bsum, h, c, cur,
                                        is_think, think_steps, out_steps, nullptr, nullptr);

  dim3 gG(NGATE/64, BATCH/64, 2);
  dim3 gG1(NGATE/64, BATCH/64, 1);
  dim3 gF(VOCAB/64, BATCH/64, 1);

  for (int t = 0; t < TENC; ++t){
    gemm_mfma<3><<<gG, 256, 0, stream>>>(x + (size_t)t*HID, TENC*HID, h, W_ih, W_hh, g0, g1, NGATE);
    cell_kernel<<<1024, 256, 0, stream>>>(g0, g1, bsum, h, c, nullptr, lengths, t);
  }
  for (int t = 0; t < TDEC; ++t){
    if (t < MAXTHINK){
      gemm_mfma<3><<<gG, 256, 0, stream>>>(cur, HID, h, W_ih, W_hh, g0, g1, NGATE);
      cell_kernel<<<1024, 256, 0, stream>>>(g0, g1, bsum, h, c, nullptr, nullptr, 0);
      gemm_mfma<3><<<gF, 256, 0, stream>>>(h, HID, nullptr, W_fc, nullptr, logits, nullptr, VOCAB);
    } else {
      gemm_mfma<1><<<gG1, 256, 0, stream>>>(h, HID, nullptr, W_hh, nullptr, g1, nullptr, NGATE);
      cell_out_kernel<<<1024, 256, 0, stream>>>(g1, bsum, W_ih, pred, h, c, nullptr);
      gemm_mfma<1><<<gF, 256, 0, stream>>>(h, HID, nullptr, W_fc, nullptr, logits, nullptr, VOCAB);
    }
    decide_kernel<<<BATCH, 256, 0, stream>>>(logits, b_fc, t,
                                             is_think + (t&1)*BATCH, is_think + ((t+1)&1)*BATCH,
                                             think_steps, out_steps, pred, cur, out, nullptr);
  }
}